// Round 2
// baseline (487.997 us; speedup 1.0000x reference)
//
#include <hip/hip_runtime.h>

// out[i, j] = softmax_j( cid_time[current[i], history[j]] )
// STATE_LEN=4096 rows, SEQ_LEN=4096 cols, cid_time 10000x10000 fp32.
//
// One 256-thread block per row:
//   1. history indices -> registers (int4, coalesced)
//   2. full 40KB cid_time row -> LDS (float4, coalesced)  [random gather would
//      touch ~all of the row's cache lines anyway -- same bytes, better pattern]
//   3. gather from LDS, block max/sum reductions, float4 stores.

constexpr int SEQ_LEN   = 4096;
constexpr int STATE_LEN = 4096;
constexpr int N_TIME    = 10000;
constexpr int THREADS   = 256;
constexpr int VPT       = SEQ_LEN / THREADS;   // 16 outputs per thread
constexpr int V4PT      = VPT / 4;             // 4 float4 groups per thread
constexpr int ROW_F4    = N_TIME / 4;          // 2500 float4 per row (40000B %16 == 0)

__global__ __launch_bounds__(THREADS) void attn_cid_time_kernel(
    const int*   __restrict__ history,   // [SEQ_LEN]
    const int*   __restrict__ current,   // [STATE_LEN]
    const float* __restrict__ cid_time,  // [N_CID, N_TIME]
    float*       __restrict__ out)       // [STATE_LEN, SEQ_LEN]
{
    __shared__ float row[N_TIME];        // 40000 B
    __shared__ float red[4];

    const int t   = threadIdx.x;
    const int rid = blockIdx.x;

    // ---- 1. history indices -> registers (thread t owns j = 4*(t + k*256) + 0..3)
    int4 hidx[V4PT];
    const int4* __restrict__ h4 = reinterpret_cast<const int4*>(history);
#pragma unroll
    for (int k = 0; k < V4PT; ++k)
        hidx[k] = h4[t + k * THREADS];

    // ---- 2. stage full row into LDS (coalesced float4)
    const long long cid = (long long)current[rid];
    const float4* __restrict__ s4 =
        reinterpret_cast<const float4*>(cid_time + cid * (long long)N_TIME);
    float4* __restrict__ row4 = reinterpret_cast<float4*>(row);
    for (int i = t; i < ROW_F4; i += THREADS)
        row4[i] = s4[i];
    __syncthreads();

    // ---- 3. gather + running max
    float v[VPT];
    float m = -3.402823466e+38f;
#pragma unroll
    for (int k = 0; k < V4PT; ++k) {
        v[4*k + 0] = row[hidx[k].x];
        v[4*k + 1] = row[hidx[k].y];
        v[4*k + 2] = row[hidx[k].z];
        v[4*k + 3] = row[hidx[k].w];
        m = fmaxf(m, fmaxf(fmaxf(v[4*k+0], v[4*k+1]), fmaxf(v[4*k+2], v[4*k+3])));
    }

    // ---- block max reduction (wave64 butterfly + 4-slot LDS)
#pragma unroll
    for (int off = 32; off >= 1; off >>= 1)
        m = fmaxf(m, __shfl_xor(m, off, 64));
    const int wid  = t >> 6;
    const int lane = t & 63;
    if (lane == 0) red[wid] = m;
    __syncthreads();
    m = fmaxf(fmaxf(red[0], red[1]), fmaxf(red[2], red[3]));
    __syncthreads();                      // red[] reused below

    // ---- exp + running sum
    float s = 0.0f;
#pragma unroll
    for (int k = 0; k < VPT; ++k) {
        const float e = __expf(v[k] - m);
        v[k] = e;
        s += e;
    }

    // ---- block sum reduction
#pragma unroll
    for (int off = 32; off >= 1; off >>= 1)
        s += __shfl_xor(s, off, 64);
    if (lane == 0) red[wid] = s;
    __syncthreads();
    s = (red[0] + red[1]) + (red[2] + red[3]);
    const float inv = 1.0f / s;

    // ---- normalized float4 stores
    float4* __restrict__ dst4 =
        reinterpret_cast<float4*>(out + (long long)rid * SEQ_LEN);
#pragma unroll
    for (int k = 0; k < V4PT; ++k) {
        float4 o;
        o.x = v[4*k + 0] * inv;
        o.y = v[4*k + 1] * inv;
        o.z = v[4*k + 2] * inv;
        o.w = v[4*k + 3] * inv;
        dst4[t + k * THREADS] = o;
    }
}

extern "C" void kernel_launch(void* const* d_in, const int* in_sizes, int n_in,
                              void* d_out, int out_size, void* d_ws, size_t ws_size,
                              hipStream_t stream) {
    const int*   history  = (const int*)d_in[0];
    const int*   current  = (const int*)d_in[1];
    const float* cid_time = (const float*)d_in[2];
    float*       out      = (float*)d_out;

    attn_cid_time_kernel<<<STATE_LEN, THREADS, 0, stream>>>(history, current, cid_time, out);
}

// Round 3
// 486.219 us; speedup vs baseline: 1.0037x; 1.0037x over previous
//
#include <hip/hip_runtime.h>

// out[i, j] = softmax_j( cid_time[current[i], history[j]] )
// STATE_LEN=4096 rows, SEQ_LEN=4096 cols, cid_time 10000x10000 fp32.
//
// One 512-thread block per row (4 blocks/CU by 40KB LDS -> 32 waves/CU, max occ):
//   1. history indices -> registers (int4, coalesced)
//   2. full 40KB cid_time row -> LDS via global_load_lds width=16 DMA
//      (39 x 1024B wave-chunks + 64B scalar tail, no VGPR round-trip)
//   3. gather from LDS, block max/sum reductions, float4 stores.

constexpr int SEQ_LEN    = 4096;
constexpr int STATE_LEN  = 4096;
constexpr int N_TIME     = 10000;
constexpr int THREADS    = 512;
constexpr int NWAVES     = THREADS / 64;          // 8
constexpr int VPT        = SEQ_LEN / THREADS;     // 8 outputs per thread
constexpr int V4PT       = VPT / 4;               // 2 float4 groups per thread
constexpr int ROW_BYTES  = N_TIME * 4;            // 40000
constexpr int CHUNK      = 64 * 16;               // 1024 B per wave DMA issue
constexpr int NFULL      = ROW_BYTES / CHUNK;     // 39 full chunks (39936 B)
constexpr int TAIL_BASE  = (NFULL * CHUNK) / 4;   // 9984 (first tail element)
constexpr int TAIL_ELEMS = N_TIME - TAIL_BASE;    // 16

__global__ __launch_bounds__(THREADS, 8) void attn_cid_time_kernel(
    const int*   __restrict__ history,   // [SEQ_LEN]
    const int*   __restrict__ current,   // [STATE_LEN]
    const float* __restrict__ cid_time,  // [N_CID, N_TIME]
    float*       __restrict__ out)       // [STATE_LEN, SEQ_LEN]
{
    __shared__ alignas(16) float row[N_TIME];     // 40000 B
    __shared__ float red[NWAVES];

    const int t    = threadIdx.x;
    const int rid  = blockIdx.x;
    const int wid  = t >> 6;
    const int lane = t & 63;

    // ---- 1. history indices -> registers (thread t owns j = 4*(t + k*512) + 0..3)
    int4 hidx[V4PT];
    const int4* __restrict__ h4 = reinterpret_cast<const int4*>(history);
#pragma unroll
    for (int k = 0; k < V4PT; ++k)
        hidx[k] = h4[t + k * THREADS];

    // ---- 2. stage full row into LDS via global_load_lds (width 16)
    const long long cid = (long long)current[rid];
    const float* __restrict__ src = cid_time + cid * (long long)N_TIME;
    const char*  srcb = reinterpret_cast<const char*>(src);
    char*        rowb = reinterpret_cast<char*>(row);

    for (int c = wid; c < NFULL; c += NWAVES) {
        __builtin_amdgcn_global_load_lds(
            (const __attribute__((address_space(1))) unsigned int*)(srcb + c * CHUNK + lane * 16),
            (__attribute__((address_space(3))) unsigned int*)(rowb + c * CHUNK),
            16, 0, 0);
    }
    // 64 B tail (elements 9984..9999): plain scalar copy
    if (t < TAIL_ELEMS)
        row[TAIL_BASE + t] = src[TAIL_BASE + t];
    __syncthreads();   // drains vmcnt (DMA) + lgkmcnt before gather

    // ---- 3. gather + running max
    float v[VPT];
    float m = -3.402823466e+38f;
#pragma unroll
    for (int k = 0; k < V4PT; ++k) {
        v[4*k + 0] = row[hidx[k].x];
        v[4*k + 1] = row[hidx[k].y];
        v[4*k + 2] = row[hidx[k].z];
        v[4*k + 3] = row[hidx[k].w];
        m = fmaxf(m, fmaxf(fmaxf(v[4*k+0], v[4*k+1]), fmaxf(v[4*k+2], v[4*k+3])));
    }

    // ---- block max reduction (wave64 butterfly + NWAVES-slot LDS)
#pragma unroll
    for (int off = 32; off >= 1; off >>= 1)
        m = fmaxf(m, __shfl_xor(m, off, 64));
    if (lane == 0) red[wid] = m;
    __syncthreads();
#pragma unroll
    for (int w = 0; w < NWAVES; ++w)
        m = fmaxf(m, red[w]);
    __syncthreads();                      // red[] reused below

    // ---- exp + running sum
    float s = 0.0f;
#pragma unroll
    for (int k = 0; k < VPT; ++k) {
        const float e = __expf(v[k] - m);
        v[k] = e;
        s += e;
    }

    // ---- block sum reduction
#pragma unroll
    for (int off = 32; off >= 1; off >>= 1)
        s += __shfl_xor(s, off, 64);
    if (lane == 0) red[wid] = s;
    __syncthreads();
    float tot = 0.0f;
#pragma unroll
    for (int w = 0; w < NWAVES; ++w)
        tot += red[w];
    const float inv = 1.0f / tot;

    // ---- normalized float4 stores
    float4* __restrict__ dst4 =
        reinterpret_cast<float4*>(out + (long long)rid * SEQ_LEN);
#pragma unroll
    for (int k = 0; k < V4PT; ++k) {
        float4 o;
        o.x = v[4*k + 0] * inv;
        o.y = v[4*k + 1] * inv;
        o.z = v[4*k + 2] * inv;
        o.w = v[4*k + 3] * inv;
        dst4[t + k * THREADS] = o;
    }
}

extern "C" void kernel_launch(void* const* d_in, const int* in_sizes, int n_in,
                              void* d_out, int out_size, void* d_ws, size_t ws_size,
                              hipStream_t stream) {
    const int*   history  = (const int*)d_in[0];
    const int*   current  = (const int*)d_in[1];
    const float* cid_time = (const float*)d_in[2];
    float*       out      = (float*)d_out;

    attn_cid_time_kernel<<<STATE_LEN, THREADS, 0, stream>>>(history, current, cid_time, out);
}